// Round 1
// baseline (113.493 us; speedup 1.0000x reference)
//
#include <hip/hip_runtime.h>
#include <hip/hip_bf16.h>

#define NB 32
#define NC 128
#define NW 128
#define NH 128
#define BCH (NB * NC * NH)

// One block per (b,c) channel; threadIdx.x = h (and = w for the staging load).
// LDS tile per w: (d, alpha*log2e, log2(m), x)  -- one broadcast ds_read_b128
// per inner iteration, conflict-free (all lanes read the same address).
//
// Math (base 2 throughout, since v_exp_f32/v_log_f32 are exp2/log2):
//   s2    = log2(m) - A2*t^2          (= s * log2e),  t = d - ref_t[h]
//   m1    = max_w s2                   (pass A)
//   e1    = exp2(s2 - m1)              -> sum1, acc1
//   st'   = 10*s2 - 9*L2 - 10*m1      (= (s_t - 10*m1)*log2e; bounded in
//            [-inf, 62*log2e], peak term >= 1 -> no overflow/total underflow)
//   e2    = exp2(st')                  -> sum2, acc2
//   y     = acc1/sum1
//   w_out = (m1 + log2(sum1)) * ln2
//   y_t   = acc2/sum2                  (shift cancels)
__global__ __launch_bounds__(NH) void sci_kernel(
    const void* __restrict__ xp, const void* __restrict__ dp,
    const void* __restrict__ mp, const void* __restrict__ kp,
    void* __restrict__ outp)
{
    const int bc  = blockIdx.x;   // 0 .. B*C-1
    const int tid = threadIdx.x;  // 0 .. 127

    __shared__ float4 tile[NW];

    // ---- dtype detection (wave-uniform, deterministic) ----
    // If d is bf16, even-indexed ushorts are real d values in [0,128].
    // If d is fp32, even-indexed ushorts are low mantissa halves -> as bf16
    // they have effectively random sign/exponent; 32 checks all passing has
    // probability ~1e-19.
    const unsigned short* du16 = (const unsigned short*)dp;
    bool is_bf16 = true;
    #pragma unroll
    for (int i = 0; i < 64; i += 2) {
        float v = __uint_as_float(((unsigned int)du16[i]) << 16);
        is_bf16 = is_bf16 && (v >= 0.0f) && (v <= 129.0f);
    }

    // ---- stage per-(b,c) data into LDS ----
    const int base = bc * NW + tid;
    float dv, mv, xv, kv;
    if (is_bf16) {
        dv = __bfloat162float(((const __hip_bfloat16*)dp)[base]);
        mv = __bfloat162float(((const __hip_bfloat16*)mp)[base]);
        xv = __bfloat162float(((const __hip_bfloat16*)xp)[base]);
        kv = __bfloat162float(((const __hip_bfloat16*)kp)[tid]);
    } else {
        dv = ((const float*)dp)[base];
        mv = ((const float*)mp)[base];
        xv = ((const float*)xp)[base];
        kv = ((const float*)kp)[tid];
    }

    const float LOG2E = 1.4426950408889634f;
    float alpha = log1pf(__expf(kv));            // softplus(kernel[w])
    float A2 = alpha * LOG2E;
    float L2 = __builtin_amdgcn_logf(mv);        // log2(m)
    tile[tid] = make_float4(dv, A2, L2, xv);
    __syncthreads();

    // ref_t = linspace(0, H, H) -> step H/(H-1)
    const float rh = (float)tid * (128.0f / 127.0f);

    // ---- pass A: m1 = max_w s2 ----
    float m1 = -3.0e38f;
    #pragma unroll 16
    for (int w = 0; w < NW; ++w) {
        float4 q = tile[w];
        float t = q.x - rh;
        float s2 = __builtin_fmaf(-q.y, t * t, q.z);
        m1 = fmaxf(m1, s2);
    }

    const float c = -10.0f * m1;

    // ---- pass B: both softmax accumulations ----
    float sum1 = 0.0f, acc1 = 0.0f, sum2 = 0.0f, acc2 = 0.0f;
    #pragma unroll 8
    for (int w = 0; w < NW; ++w) {
        float4 q = tile[w];
        float t  = q.x - rh;
        float t2 = t * t;
        float s2 = __builtin_fmaf(-q.y, t2, q.z);
        float sm = s2 - m1;
        float e1 = __builtin_amdgcn_exp2f(sm);
        float r  = __builtin_fmaf(10.0f, s2, c);
        float st = __builtin_fmaf(-9.0f, q.z, r);
        float e2 = __builtin_amdgcn_exp2f(st);
        sum1 += e1;
        acc1 = __builtin_fmaf(e1, q.w, acc1);
        sum2 += e2;
        acc2 = __builtin_fmaf(e2, q.w, acc2);
    }

    const float LN2 = 0.6931471805599453f;
    float y  = acc1 / sum1;
    float wv = (m1 + __builtin_amdgcn_logf(sum1)) * LN2;
    float yt = acc2 / sum2;

    const int o = bc * NH + tid;
    if (is_bf16) {
        __hip_bfloat16* o16 = (__hip_bfloat16*)outp;
        o16[o]           = __float2bfloat16(y);
        o16[BCH + o]     = __float2bfloat16(wv);
        o16[2 * BCH + o] = __float2bfloat16(yt);
    } else {
        float* o32 = (float*)outp;
        o32[o]           = y;
        o32[BCH + o]     = wv;
        o32[2 * BCH + o] = yt;
    }
}

extern "C" void kernel_launch(void* const* d_in, const int* in_sizes, int n_in,
                              void* d_out, int out_size, void* d_ws, size_t ws_size,
                              hipStream_t stream) {
    const void* x_t = d_in[0];
    const void* d   = d_in[1];
    const void* m   = d_in[2];
    const void* k   = d_in[3];
    dim3 grid(NB * NC);
    dim3 block(NH);
    hipLaunchKernelGGL(sci_kernel, grid, block, 0, stream, x_t, d, m, k, d_out);
}

// Round 2
// 85.800 us; speedup vs baseline: 1.3228x; 1.3228x over previous
//
#include <hip/hip_runtime.h>
#include <hip/hip_bf16.h>

#define NB 32
#define NC 128
#define NW 128
#define NH 128
#define BCH (NB * NC * NH)

// One 64-thread (1-wave) block per (b,c) channel; thread t handles h=t and
// h=t+64, so every broadcast LDS read is amortized over 2 h-computations.
//
// Math (base 2): s2 = log2(m) - A2*t^2, t = d - ref_t[h], A2 = alpha*log2e.
// Shift M = max_w(-A2*t^2) = -mn, mn = min_w(A2*t^2).  M >= max_w s2 (since
// log2(m) <= 0) and overshoots by <= -log2(m_min) <= 10, so:
//   v   = mn - A2*t^2  (<= 0 for all w  ->  exp2 never overflows)
//   e1  = exp2(s2 - M)          = m * exp2(v)
//   e2  = exp2(10*s2 - 9*L2 - 10*M) = m * exp2(10*v)   (kappa=10 path)
// Peak kappa term >= 2^-100 -> no 0/0. The shift cancels in y, y_t, and
// w = (M + log2(sum1)) * ln2. log2(m) never appears in the hot loop.
__global__ __launch_bounds__(64) void sci_kernel(
    const void* __restrict__ xp, const void* __restrict__ dp,
    const void* __restrict__ mp, const void* __restrict__ kp,
    void* __restrict__ outp)
{
    const int bc  = blockIdx.x;   // 0 .. B*C-1
    const int tid = threadIdx.x;  // 0 .. 63

    __shared__ float4 tileB[NW];  // (d, A2, m, m*x)
    __shared__ float2 tileA[NW];  // (d, A2)

    // ---- dtype detection (wave-uniform, deterministic) ----
    const unsigned short* du16 = (const unsigned short*)dp;
    bool is_bf16 = true;
    #pragma unroll
    for (int i = 0; i < 64; i += 2) {
        float v = __uint_as_float(((unsigned int)du16[i]) << 16);
        is_bf16 = is_bf16 && (v >= 0.0f) && (v <= 129.0f);
    }

    // ---- stage per-(b,c) data into LDS (2 w per thread) ----
    const float LOG2E = 1.4426950408889634f;
    #pragma unroll
    for (int j = 0; j < 2; ++j) {
        const int w = tid + j * 64;
        const int base = bc * NW + w;
        float dv, mv, xv, kv;
        if (is_bf16) {
            dv = __bfloat162float(((const __hip_bfloat16*)dp)[base]);
            mv = __bfloat162float(((const __hip_bfloat16*)mp)[base]);
            xv = __bfloat162float(((const __hip_bfloat16*)xp)[base]);
            kv = __bfloat162float(((const __hip_bfloat16*)kp)[w]);
        } else {
            dv = ((const float*)dp)[base];
            mv = ((const float*)mp)[base];
            xv = ((const float*)xp)[base];
            kv = ((const float*)kp)[w];
        }
        float alpha = log1pf(__expf(kv));   // softplus(kernel[w])
        float A2 = alpha * LOG2E;
        tileB[w] = make_float4(dv, A2, mv, mv * xv);
        tileA[w] = make_float2(dv, A2);
    }
    __syncthreads();

    // ref_t = linspace(0, H, H) -> step H/(H-1)
    const float rh0 = (float)tid * (128.0f / 127.0f);
    const float rh1 = (float)(tid + 64) * (128.0f / 127.0f);

    // ---- pass A: mn = min_w A2*t^2 for both h ----
    float mn0 = 3.0e38f, mn1 = 3.0e38f;
    #pragma unroll 16
    for (int w = 0; w < NW; ++w) {
        float2 q = tileA[w];
        float t0 = q.x - rh0;
        float t1 = q.x - rh1;
        mn0 = fminf(mn0, q.y * (t0 * t0));
        mn1 = fminf(mn1, q.y * (t1 * t1));
    }

    // ---- pass B: both softmaxes for both h ----
    float s10 = 0.f, a10 = 0.f, s20 = 0.f, a20 = 0.f;
    float s11 = 0.f, a11 = 0.f, s21 = 0.f, a21 = 0.f;
    #pragma unroll 4
    for (int w = 0; w < NW; ++w) {
        float4 q = tileB[w];
        {
            float t  = q.x - rh0;
            float v  = __builtin_fmaf(-q.y, t * t, mn0);
            float g1 = __builtin_amdgcn_exp2f(v);
            float g2 = __builtin_amdgcn_exp2f(10.0f * v);
            s10 = __builtin_fmaf(q.z, g1, s10);
            a10 = __builtin_fmaf(q.w, g1, a10);
            s20 = __builtin_fmaf(q.z, g2, s20);
            a20 = __builtin_fmaf(q.w, g2, a20);
        }
        {
            float t  = q.x - rh1;
            float v  = __builtin_fmaf(-q.y, t * t, mn1);
            float g1 = __builtin_amdgcn_exp2f(v);
            float g2 = __builtin_amdgcn_exp2f(10.0f * v);
            s11 = __builtin_fmaf(q.z, g1, s11);
            a11 = __builtin_fmaf(q.w, g1, a11);
            s21 = __builtin_fmaf(q.z, g2, s21);
            a21 = __builtin_fmaf(q.w, g2, a21);
        }
    }

    const float LN2 = 0.6931471805599453f;
    float y0  = a10 * __builtin_amdgcn_rcpf(s10);
    float y1  = a11 * __builtin_amdgcn_rcpf(s11);
    float w0  = (__builtin_amdgcn_logf(s10) - mn0) * LN2;  // (M + log2 sum)*ln2, M=-mn
    float w1  = (__builtin_amdgcn_logf(s11) - mn1) * LN2;
    float yt0 = a20 * __builtin_amdgcn_rcpf(s20);
    float yt1 = a21 * __builtin_amdgcn_rcpf(s21);

    const int o0 = bc * NH + tid;
    const int o1 = o0 + 64;
    if (is_bf16) {
        __hip_bfloat16* o16 = (__hip_bfloat16*)outp;
        o16[o0]           = __float2bfloat16(y0);
        o16[o1]           = __float2bfloat16(y1);
        o16[BCH + o0]     = __float2bfloat16(w0);
        o16[BCH + o1]     = __float2bfloat16(w1);
        o16[2 * BCH + o0] = __float2bfloat16(yt0);
        o16[2 * BCH + o1] = __float2bfloat16(yt1);
    } else {
        float* o32 = (float*)outp;
        o32[o0]           = y0;
        o32[o1]           = y1;
        o32[BCH + o0]     = w0;
        o32[BCH + o1]     = w1;
        o32[2 * BCH + o0] = yt0;
        o32[2 * BCH + o1] = yt1;
    }
}

extern "C" void kernel_launch(void* const* d_in, const int* in_sizes, int n_in,
                              void* d_out, int out_size, void* d_ws, size_t ws_size,
                              hipStream_t stream) {
    const void* x_t = d_in[0];
    const void* d   = d_in[1];
    const void* m   = d_in[2];
    const void* k   = d_in[3];
    dim3 grid(NB * NC);
    dim3 block(64);
    hipLaunchKernelGGL(sci_kernel, grid, block, 0, stream, x_t, d, m, k, d_out);
}